// Round 5
// baseline (307.816 us; speedup 1.0000x reference)
//
#include <hip/hip_runtime.h>
#include <stdint.h>

#define L_SEQ 256
#define E_DIM 64
#define N_B   64
#define LN_EPS 1e-5f

typedef float f4 __attribute__((ext_vector_type(4)));

// ---------------------------------------------------------------------------
// K1: one block per n (grid 64 x 256 threads, 128 KB LDS).
//   energy[a,b] = sum_l Q[n,l,a]*K[n,l,b] ; attn = softmax over b (hd==1)
//   P[k][e]    = sum_q attn[q][k] * W_out[e][q]     (64^3 tiny GEMM)
//   wsP[n][k][e] = P                                 (1 MB total)
// ---------------------------------------------------------------------------
__global__ __launch_bounds__(256) void attn_p_kernel(
    const float* __restrict__ gq,
    const float* __restrict__ gk,
    const float* __restrict__ gw,
    float*       __restrict__ wsP)
{
    __shared__ float lds[32768];          // 128 KB
    float* Qs    = lds;                   // phase1: [l][a], 16384 floats
    float* Ks    = lds + 16384;           // phase1: [l][b], 16384 floats
    float* attnS = lds;                   // phase2: [q][k], 4096 (over Qs)
    float* WtS   = lds + 4096;            // phase2: [q][e] stride 68

    const int t = threadIdx.x;
    const int n = blockIdx.x;
    const float* qb = gq + (size_t)n * (L_SEQ * E_DIM);
    const float* kb = gk + (size_t)n * (L_SEQ * E_DIM);

    // ---- stage Q,K (coalesced f4): 4096 f4 per tile, 16 per thread ----
    #pragma unroll
    for (int i = 0; i < 16; ++i) {
        reinterpret_cast<f4*>(Qs)[t + 256 * i] =
            reinterpret_cast<const f4*>(qb)[t + 256 * i];
        reinterpret_cast<f4*>(Ks)[t + 256 * i] =
            reinterpret_cast<const f4*>(kb)[t + 256 * i];
    }
    __syncthreads();

    const int tx = t & 15, ty = t >> 4;   // tx -> b-tile, ty -> a-tile
    const int b0 = tx * 4, a0 = ty * 4;

    // ---- energy: 4x4 tile per thread ----
    float acc[4][4] = {};
    #pragma unroll 8
    for (int l = 0; l < L_SEQ; ++l) {
        f4 qa = *reinterpret_cast<const f4*>(&Qs[l * E_DIM + a0]);
        f4 kv = *reinterpret_cast<const f4*>(&Ks[l * E_DIM + b0]);
        #pragma unroll
        for (int ia = 0; ia < 4; ++ia)
            #pragma unroll
            for (int ib = 0; ib < 4; ++ib)
                acc[ia][ib] = fmaf(qa[ia], kv[ib], acc[ia][ib]);
    }

    // ---- softmax over b; row a0+ia spread over the 16 tx lanes ----
    #pragma unroll
    for (int ia = 0; ia < 4; ++ia) {
        float m = fmaxf(fmaxf(acc[ia][0], acc[ia][1]),
                        fmaxf(acc[ia][2], acc[ia][3]));
        #pragma unroll
        for (int s = 1; s <= 8; s <<= 1) m = fmaxf(m, __shfl_xor(m, s));
        float e0v = __expf(acc[ia][0] - m);
        float e1v = __expf(acc[ia][1] - m);
        float e2v = __expf(acc[ia][2] - m);
        float e3v = __expf(acc[ia][3] - m);
        float ssum = (e0v + e1v) + (e2v + e3v);
        #pragma unroll
        for (int s = 1; s <= 8; s <<= 1) ssum += __shfl_xor(ssum, s);
        float inv = 1.0f / ssum;
        acc[ia][0] = e0v * inv; acc[ia][1] = e1v * inv;
        acc[ia][2] = e2v * inv; acc[ia][3] = e3v * inv;
    }

    __syncthreads();   // all lanes done reading Qs/Ks before LDS reuse

    // ---- attnS[q][k] rows (f4), q = a0+ia ----
    #pragma unroll
    for (int ia = 0; ia < 4; ++ia) {
        f4 v4 = {acc[ia][0], acc[ia][1], acc[ia][2], acc[ia][3]};
        *reinterpret_cast<f4*>(&attnS[(a0 + ia) * 64 + b0]) = v4;
    }

    // ---- WtS[q][e] = W_out[e][q], stride 68 (rows 16B-aligned: 68*4=272) --
    #pragma unroll
    for (int i = 0; i < 16; ++i) {
        int idx = t + 256 * i;            // = e*64 + q
        WtS[(idx & 63) * 68 + (idx >> 6)] = gw[idx];
    }
    __syncthreads();

    // ---- P[k][e] = sum_q attn[q][k] * Wt[q][e]; 4k x 4e per thread ----
    const int k0 = ty * 4, e0 = tx * 4;
    float pacc[4][4] = {};
    #pragma unroll 8
    for (int q = 0; q < 64; ++q) {
        f4 av = *reinterpret_cast<const f4*>(&attnS[q * 64 + k0]);
        f4 wv = *reinterpret_cast<const f4*>(&WtS[q * 68 + e0]);
        #pragma unroll
        for (int ik = 0; ik < 4; ++ik)
            #pragma unroll
            for (int ie = 0; ie < 4; ++ie)
                pacc[ik][ie] = fmaf(av[ik], wv[ie], pacc[ik][ie]);
    }
    float* pb = wsP + (size_t)n * 4096 + e0;
    #pragma unroll
    for (int ik = 0; ik < 4; ++ik) {
        f4 v4 = {pacc[ik][0], pacc[ik][1], pacc[ik][2], pacc[ik][3]};
        *reinterpret_cast<f4*>(pb + (size_t)(k0 + ik) * 64) = v4;
    }
}

// ---------------------------------------------------------------------------
// K2: grid 1024 (n = b>>4, 16-row l-chunk = b&15) x 256 threads.
//   fc[l][e] = sum_k values[k,l,n] * P[n][k][e] + b[e]
//   M[l][e]  = LN_e(fc[l][:])   (+query residual const over e -> cancels)
//   broadcast M row to all 64 h slices: out[h][n][l][e]  (PLAIN stores —
//   R4 showed nontemporal throttles the write stream vs the fill kernel).
// Deleting the separate bcast kernel removes the 4 MB ws2 round-trip,
// the 32 MB L2 re-read, and one launch gap.
// ---------------------------------------------------------------------------
__global__ __launch_bounds__(256) void fc_ln_bcast_kernel(
    const float* __restrict__ gv,
    const float* __restrict__ gbo,
    const float* __restrict__ glnw,
    const float* __restrict__ glnb,
    const float* __restrict__ wsP,
    float*       __restrict__ gout)
{
    __shared__ float PS[64 * 64];     // [k][e], 16 KB
    __shared__ float VnS[64 * 16];    // [k][l'], 4 KB

    const int t  = threadIdx.x;
    const int b  = blockIdx.x;
    const int n  = b >> 4;
    const int l0 = (b & 15) * 16;

    // stage P[n] (coalesced f4: 1024 f4, 4 per thread)
    const f4* psrc = reinterpret_cast<const f4*>(wsP + (size_t)n * 4096);
    #pragma unroll
    for (int i = 0; i < 4; ++i)
        reinterpret_cast<f4*>(PS)[t + 256 * i] = psrc[t + 256 * i];

    // stage VnS[k][l'] = values[k, l0+l', n]  (scattered, L2/L3-resident)
    #pragma unroll
    for (int i = 0; i < 4; ++i) {
        int idx = t + 256 * i;
        int lp = idx & 15, k = idx >> 4;
        VnS[k * 16 + lp] =
            gv[(size_t)k * (L_SEQ * E_DIM) + (size_t)(l0 + lp) * E_DIM + n];
    }
    __syncthreads();

    const int tx = t & 15, ty = t >> 4;   // ty -> l' row, tx -> e-quad
    const int e0 = tx * 4;

    float fc0 = 0.f, fc1 = 0.f, fc2 = 0.f, fc3 = 0.f;
    #pragma unroll 8
    for (int k = 0; k < 64; ++k) {
        float v = VnS[k * 16 + ty];                      // LDS broadcast
        f4 p4 = *reinterpret_cast<const f4*>(&PS[k * 64 + e0]);
        fc0 = fmaf(v, p4[0], fc0);
        fc1 = fmaf(v, p4[1], fc1);
        fc2 = fmaf(v, p4[2], fc2);
        fc3 = fmaf(v, p4[3], fc3);
    }

    f4 be = *reinterpret_cast<const f4*>(&gbo[e0]);
    f4 lw = *reinterpret_cast<const f4*>(&glnw[e0]);
    f4 lb = *reinterpret_cast<const f4*>(&glnb[e0]);

    float v0 = fc0 + be[0];
    float v1 = fc1 + be[1];
    float v2 = fc2 + be[2];
    float v3 = fc3 + be[3];

    // LN over e: row ty spread across the 16 tx lanes (same wave)
    float s1 = (v0 + v1) + (v2 + v3);
    float s2 = (v0 * v0 + v1 * v1) + (v2 * v2 + v3 * v3);
    #pragma unroll
    for (int s = 1; s <= 8; s <<= 1) {
        s1 += __shfl_xor(s1, s);
        s2 += __shfl_xor(s2, s);
    }
    float mu  = s1 * (1.0f / 64.0f);
    float var = s2 * (1.0f / 64.0f) - mu * mu;
    float rs  = rsqrtf(var + LN_EPS);
    f4 o;
    o[0] = (v0 - mu) * rs * lw[0] + lb[0];
    o[1] = (v1 - mu) * rs * lw[1] + lb[1];
    o[2] = (v2 - mu) * rs * lw[2] + lb[2];
    o[3] = (v3 - mu) * rs * lw[3] + lb[3];

    // broadcast to all 64 h slices; per wave per h: 1 KB contiguous stores
    f4* op = reinterpret_cast<f4*>(
        gout + (size_t)n * (L_SEQ * E_DIM) + (size_t)(l0 + ty) * E_DIM + e0);
    const size_t hstride4 = (size_t)N_B * L_SEQ * E_DIM / 4;  // in f4 units
    #pragma unroll 8
    for (int h = 0; h < 64; ++h) {
        *op = o;
        op += hstride4;
    }
}

extern "C" void kernel_launch(void* const* d_in, const int* in_sizes, int n_in,
                              void* d_out, int out_size, void* d_ws, size_t ws_size,
                              hipStream_t stream)
{
    const float* gv  = (const float*)d_in[0];  // values  [N,L,E] f32
    const float* gk  = (const float*)d_in[1];  // keys    [N,L,E]
    const float* gq  = (const float*)d_in[2];  // query   [N,L,E]
    const float* gw  = (const float*)d_in[3];  // W_out   [E,E]
    const float* gbo = (const float*)d_in[4];  // b_out   [E]
    const float* glw = (const float*)d_in[5];  // ln_w    [E]
    const float* glb = (const float*)d_in[6];  // ln_b    [E]
    float* wsP = (float*)d_ws;                 // P: 64*64*64 f32 = 1 MiB
    float* out = (float*)d_out;                // [H,N,L,E] f32

    hipLaunchKernelGGL(attn_p_kernel, dim3(64), dim3(256), 0, stream,
                       gq, gk, gw, wsP);
    hipLaunchKernelGGL(fc_ln_bcast_kernel, dim3(1024), dim3(256), 0, stream,
                       gv, gbo, glw, glb, wsP, out);
}